// Round 1
// baseline (386.746 us; speedup 1.0000x reference)
//
#include <hip/hip_runtime.h>

// FastfoodProjection: out = (1/8192) * H * diag(G) * P * H * diag(B) * pad(x)
// per row; H = Hadamard_8192, x rows of 4096 padded to 8192, out rows 8192.
//
// Design: one block (256 threads) per row. Each thread holds 32 elements in
// registers (r = m*2 + e; bit 0 of the logical index always lives in e so all
// LDS exchanges move float2 / b64). FWHT bits (commutative butterflies) split
// into 3 register phases per FWHT:
//   A: bits {0, 9,10,11,12}   j = m*512 + 2t + e     (global load layout)
//   B: bits {0passive, 1..4}  j = t*32  + 2m + e
//   C: bits {0passive, 5..8}  j = (t>>4)*512 + m*32 + (t&15)*2 + e
// => 2 LDS exchanges per FWHT + 1 LDS roundtrip for the permutation gather.
// LDS padded +2 words per 32 (p(w) = w + 2*(w>>5)): keeps b64 exchanges
// bank-conflict-free and 8B-aligned.

constexpr int N  = 8192;
constexpr int NT = 256;
constexpr int NR = 32;
constexpr int LDS_WORDS = N + 2 * (N / 32); // 8704 words = 34 KB

__device__ __forceinline__ int padw(int w) { return w + 2 * (w >> 5); }

template <int FIRST_MASK>
__device__ __forceinline__ void butterfly(float v[NR]) {
    #pragma unroll
    for (int b = FIRST_MASK; b < NR; b <<= 1) {
        #pragma unroll
        for (int r = 0; r < NR; ++r) {
            if ((r & b) == 0) {
                float a = v[r], c = v[r ^ b];
                v[r]     = a + c;
                v[r ^ b] = a - c;
            }
        }
    }
}

__global__ __launch_bounds__(NT) void fastfood_kernel(
    const float* __restrict__ x, const float* __restrict__ Bv,
    const float* __restrict__ Gv, const int* __restrict__ perm,
    float* __restrict__ out)
{
    __shared__ float lds[LDS_WORDS];
    const int t = threadIdx.x;
    const int row = blockIdx.x;
    const float* xrow = x + (size_t)row * 4096;
    float v[NR];

    // ---- load + B multiply, layout A: j = m*512 + 2t + e (j<4096 <=> m<8)
    #pragma unroll
    for (int m = 0; m < 8; ++m) {
        int j = m * 512 + 2 * t;
        float2 xv = *(const float2*)(xrow + j);
        float2 bv = *(const float2*)(Bv + j);
        v[2 * m]     = xv.x * bv.x;
        v[2 * m + 1] = xv.y * bv.y;
    }
    #pragma unroll
    for (int m = 8; m < 16; ++m) { v[2 * m] = 0.f; v[2 * m + 1] = 0.f; }

    // ---- FWHT #1
    butterfly<1>(v);                       // bits 0, 9..12
    #pragma unroll
    for (int m = 0; m < 16; ++m) {         // write A
        int w = m * 512 + 2 * t;
        *(float2*)&lds[padw(w)] = make_float2(v[2 * m], v[2 * m + 1]);
    }
    __syncthreads();
    #pragma unroll
    for (int m = 0; m < 16; ++m) {         // read B
        int w = t * 32 + 2 * m;
        float2 d = *(const float2*)&lds[padw(w)];
        v[2 * m] = d.x; v[2 * m + 1] = d.y;
    }
    butterfly<2>(v);                       // bits 1..4
    __syncthreads();
    #pragma unroll
    for (int m = 0; m < 16; ++m) {         // write B
        int w = t * 32 + 2 * m;
        *(float2*)&lds[padw(w)] = make_float2(v[2 * m], v[2 * m + 1]);
    }
    __syncthreads();
    #pragma unroll
    for (int m = 0; m < 16; ++m) {         // read C
        int w = (t >> 4) * 512 + m * 32 + (t & 15) * 2;
        float2 d = *(const float2*)&lds[padw(w)];
        v[2 * m] = d.x; v[2 * m + 1] = d.y;
    }
    butterfly<2>(v);                       // bits 5..8
    __syncthreads();
    #pragma unroll
    for (int m = 0; m < 16; ++m) {         // write C (FWHT1 result, all j)
        int w = (t >> 4) * 512 + m * 32 + (t & 15) * 2;
        *(float2*)&lds[padw(w)] = make_float2(v[2 * m], v[2 * m + 1]);
    }
    __syncthreads();

    // ---- permutation gather + G + combined 1/8192 normalization -> layout A
    const float scale = 1.0f / 8192.0f;
    #pragma unroll
    for (int m = 0; m < 16; ++m) {
        int j = m * 512 + 2 * t;
        int2 q = *(const int2*)(perm + j);
        float2 g = *(const float2*)(Gv + j);
        v[2 * m]     = lds[q.x + 2 * (q.x >> 5)] * g.x * scale;
        v[2 * m + 1] = lds[q.y + 2 * (q.y >> 5)] * g.y * scale;
    }

    // ---- FWHT #2
    butterfly<1>(v);                       // bits 0, 9..12
    __syncthreads();
    #pragma unroll
    for (int m = 0; m < 16; ++m) {         // write A
        int w = m * 512 + 2 * t;
        *(float2*)&lds[padw(w)] = make_float2(v[2 * m], v[2 * m + 1]);
    }
    __syncthreads();
    #pragma unroll
    for (int m = 0; m < 16; ++m) {         // read B
        int w = t * 32 + 2 * m;
        float2 d = *(const float2*)&lds[padw(w)];
        v[2 * m] = d.x; v[2 * m + 1] = d.y;
    }
    butterfly<2>(v);                       // bits 1..4
    __syncthreads();
    #pragma unroll
    for (int m = 0; m < 16; ++m) {         // write B
        int w = t * 32 + 2 * m;
        *(float2*)&lds[padw(w)] = make_float2(v[2 * m], v[2 * m + 1]);
    }
    __syncthreads();
    #pragma unroll
    for (int m = 0; m < 16; ++m) {         // read C
        int w = (t >> 4) * 512 + m * 32 + (t & 15) * 2;
        float2 d = *(const float2*)&lds[padw(w)];
        v[2 * m] = d.x; v[2 * m + 1] = d.y;
    }
    butterfly<2>(v);                       // bits 5..8

    // ---- store from layout C (16 x float2, 128B segments per instruction)
    float* orow = out + (size_t)row * 8192;
    #pragma unroll
    for (int m = 0; m < 16; ++m) {
        int j = (t >> 4) * 512 + m * 32 + (t & 15) * 2;
        *(float2*)(orow + j) = make_float2(v[2 * m], v[2 * m + 1]);
    }
}

extern "C" void kernel_launch(void* const* d_in, const int* in_sizes, int n_in,
                              void* d_out, int out_size, void* d_ws, size_t ws_size,
                              hipStream_t stream) {
    const float* x    = (const float*)d_in[0];
    const float* Bv   = (const float*)d_in[1];
    const float* Gv   = (const float*)d_in[2];
    const int*   perm = (const int*)d_in[3];
    float* out = (float*)d_out;
    fastfood_kernel<<<dim3(8192), dim3(NT), 0, stream>>>(x, Bv, Gv, perm, out);
}

// Round 2
// 377.917 us; speedup vs baseline: 1.0234x; 1.0234x over previous
//
#include <hip/hip_runtime.h>

// FastfoodProjection: out = (1/8192) * H * diag(G) * P * H * diag(B) * pad(x)
// per row; H = Hadamard_8192, x rows of 4096 padded to 8192, out rows 8192.
//
// One block (256 threads) per row; 32 elements/thread in registers
// (r = 2m + e, bit 0 of logical index j always in e => all LDS exchanges are
// float2/b64). Three register phases per FWHT (5 j-bits each):
//   A: j = m*512 + 2t + e           bits {0, 9..12}   (global load/store layout)
//   B: j = t*32  + 2m + e           bits {1..4}
//   C: j = (t>>4)*512 + m*32 + (t&15)*2 + e   bits {0(passive on 2nd use), 5..8}
// FWHT1 runs A->B->C, permutation gather lands directly in layout C,
// FWHT2 runs C->B->A so stores are fully contiguous (512 B per wave instr).
// Layouts partition j by thread, so read-X -> write-X (same layout) needs NO
// barrier: 6 __syncthreads total. 5 LDS roundtrips = structural minimum
// (2 exchanges per FWHT + 1 for the random permutation).
// LDS pad +2 words per 32 keeps all exchange patterns conflict-free and
// preserves 8 B alignment.

constexpr int N  = 8192;
constexpr int NT = 256;
constexpr int NR = 32;
constexpr int LDS_WORDS = N + 2 * (N / 32); // 8704 words = 34 KB

__device__ __forceinline__ int padw(int w) { return w + 2 * (w >> 5); }

template <int FIRST_MASK>
__device__ __forceinline__ void butterfly(float v[NR]) {
    #pragma unroll
    for (int b = FIRST_MASK; b < NR; b <<= 1) {
        #pragma unroll
        for (int r = 0; r < NR; ++r) {
            if ((r & b) == 0) {
                float a = v[r], c = v[r ^ b];
                v[r]     = a + c;
                v[r ^ b] = a - c;
            }
        }
    }
}

// __launch_bounds__(256, 4): 4 waves/SIMD min => compiler caps VGPR <= 128,
// guaranteeing 4 blocks/CU (4 x 34 KB = 136 KB LDS <= 160 KB) for cross-block
// overlap of the barrier-serial phases.
__global__ __launch_bounds__(NT, 4) void fastfood_kernel(
    const float* __restrict__ x, const float* __restrict__ Bv,
    const float* __restrict__ Gv, const int* __restrict__ perm,
    float* __restrict__ out)
{
    __shared__ float lds[LDS_WORDS];
    const int t = threadIdx.x;
    const int row = blockIdx.x;
    const float* xrow = x + (size_t)row * 4096;

    const int wA = 2 * t;                       // + m*512
    const int wB = t * 32;                      // + 2m
    const int wC = (t >> 4) * 512 + (t & 15) * 2; // + m*32

    float v[NR];

    // ---- load + B multiply, layout A (j < 4096 <=> m < 8)
    #pragma unroll
    for (int m = 0; m < 8; ++m) {
        int j = m * 512 + wA;
        float2 xv = *(const float2*)(xrow + j);
        float2 bv = *(const float2*)(Bv + j);
        v[2 * m]     = xv.x * bv.x;
        v[2 * m + 1] = xv.y * bv.y;
    }
    #pragma unroll
    for (int m = 8; m < 16; ++m) { v[2 * m] = 0.f; v[2 * m + 1] = 0.f; }

    // ---- FWHT #1: phase A (bits 0, 9..12)
    butterfly<1>(v);
    #pragma unroll
    for (int m = 0; m < 16; ++m)
        *(float2*)&lds[padw(m * 512 + wA)] = make_float2(v[2 * m], v[2 * m + 1]);
    __syncthreads();

    // phase B (bits 1..4)
    #pragma unroll
    for (int m = 0; m < 16; ++m) {
        float2 d = *(const float2*)&lds[padw(wB + 2 * m)];
        v[2 * m] = d.x; v[2 * m + 1] = d.y;
    }
    butterfly<2>(v);
    #pragma unroll
    for (int m = 0; m < 16; ++m)   // same addresses we read: no barrier needed
        *(float2*)&lds[padw(wB + 2 * m)] = make_float2(v[2 * m], v[2 * m + 1]);
    __syncthreads();

    // phase C (bits 5..8); prefetch perm (layout-C indices) to hide L2 latency
    #pragma unroll
    for (int m = 0; m < 16; ++m) {
        float2 d = *(const float2*)&lds[padw(wC + m * 32)];
        v[2 * m] = d.x; v[2 * m + 1] = d.y;
    }
    int2 q[16];
    #pragma unroll
    for (int m = 0; m < 16; ++m)
        q[m] = *(const int2*)(perm + wC + m * 32);
    butterfly<2>(v);
    #pragma unroll
    for (int m = 0; m < 16; ++m)   // same addresses we read: no barrier needed
        *(float2*)&lds[padw(wC + m * 32)] = make_float2(v[2 * m], v[2 * m + 1]);
    __syncthreads();

    // ---- permutation gather + G multiply, landing in layout C
    #pragma unroll
    for (int m = 0; m < 16; ++m) {
        float2 g = *(const float2*)(Gv + wC + m * 32);
        v[2 * m]     = lds[q[m].x + 2 * (q[m].x >> 5)] * g.x;
        v[2 * m + 1] = lds[q[m].y + 2 * (q[m].y >> 5)] * g.y;
    }

    // ---- FWHT #2: phase C (bits 0, 5..8) — butterfly before the barrier
    butterfly<1>(v);
    __syncthreads();               // all random gathers done before overwrite
    #pragma unroll
    for (int m = 0; m < 16; ++m)
        *(float2*)&lds[padw(wC + m * 32)] = make_float2(v[2 * m], v[2 * m + 1]);
    __syncthreads();

    // phase B (bits 1..4)
    #pragma unroll
    for (int m = 0; m < 16; ++m) {
        float2 d = *(const float2*)&lds[padw(wB + 2 * m)];
        v[2 * m] = d.x; v[2 * m + 1] = d.y;
    }
    butterfly<2>(v);
    #pragma unroll
    for (int m = 0; m < 16; ++m)   // same addresses we read: no barrier needed
        *(float2*)&lds[padw(wB + 2 * m)] = make_float2(v[2 * m], v[2 * m + 1]);
    __syncthreads();

    // phase A (bits 9..12)
    #pragma unroll
    for (int m = 0; m < 16; ++m) {
        float2 d = *(const float2*)&lds[padw(m * 512 + wA)];
        v[2 * m] = d.x; v[2 * m + 1] = d.y;
    }
    butterfly<2>(v);

    // ---- store, fully coalesced (512 B per wave instruction), scale folded
    const float scale = 1.0f / 8192.0f;
    float* orow = out + (size_t)row * 8192;
    #pragma unroll
    for (int m = 0; m < 16; ++m) {
        int j = m * 512 + wA;
        *(float2*)(orow + j) = make_float2(v[2 * m] * scale, v[2 * m + 1] * scale);
    }
}

extern "C" void kernel_launch(void* const* d_in, const int* in_sizes, int n_in,
                              void* d_out, int out_size, void* d_ws, size_t ws_size,
                              hipStream_t stream) {
    const float* x    = (const float*)d_in[0];
    const float* Bv   = (const float*)d_in[1];
    const float* Gv   = (const float*)d_in[2];
    const int*   perm = (const int*)d_in[3];
    float* out = (float*)d_out;
    fastfood_kernel<<<dim3(8192), dim3(NT), 0, stream>>>(x, Bv, Gv, perm, out);
}